// Round 4
// baseline (882.512 us; speedup 1.0000x reference)
//
#include <hip/hip_runtime.h>

typedef float v2f __attribute__((ext_vector_type(2)));
typedef float v4f __attribute__((ext_vector_type(4)));

#define N_IN   131072
#define K_EMB  1024
#define D_EMB  64
#define QUANT_OFF 1
#define PERP_OFF  (1 + N_IN * D_EMB)      /* 8388609 */
#define ENC_OFF   (PERP_OFF + 1)          /* 8388610: %16==8 -> float2 stores only */

// R12 = R11 resubmitted (round-3 failure was container acquisition, not the
// kernel). Hardening: k_count now takes explicit pointer args (it was the
// only zero-arg __global__ in the session). Pipeline otherwise identical.
// All static device buffers are fully rewritten every launch (re-poison safe).
__device__ float        g_Et[D_EMB * K_EMB];   // Et[d][c] transposed codebook
__device__ unsigned int g_ids[N_IN];           // argmin index per sample
#define NCBLK 32
__device__ unsigned int g_pcnt[NCBLK * K_EMB]; // partial histograms

// ws layout (4-byte units): [1024] loss accumulator, [2048..3071] half norms.

__global__ __launch_bounds__(256) void k_prep(const float* __restrict__ emb,
                                              float* __restrict__ ws) {
  int k = blockIdx.x * 256 + threadIdx.x;  // grid=4 -> k in [0,1024)
  if (k == 0) ws[1024] = 0.0f;
  const float* e = emb + (size_t)k * D_EMB;
  double s = 0.0;
  #pragma unroll
  for (int d = 0; d < D_EMB; ++d) {
    float v = e[d];
    s += (double)v * (double)v;
    g_Et[d * K_EMB + k] = v;               // coalesced per d
  }
  ws[2048 + k] = (float)(0.5 * s);
}

// ---------------------------------------------------------------------------
// k_amin: wave-autonomous argmin, output = indices only (512 KB).
// Rationale (R10 post-mortem): four structurally different fused kernels all
// ran ~350-360us because the 571MB store stream thrashes the per-XCD L2 and
// evicts the codebook -> B-stream degrades to HBM refetch. With no store
// stream here, Et (256KB) is genuinely L2-resident; bound = max(VALU 109us,
// L2 ~120us). Math bit-identical to R10 -> identical ids.
// ---------------------------------------------------------------------------

#define LOAD_A(D0,D1,row)                                \
  {                                                      \
    const float* xr_ = xrow + (row) * 8;                 \
    D0 = *(const v4f*)(xr_ + 0);                         \
    D1 = *(const v4f*)(xr_ + 4);                         \
  }

#define LOAD_B(D0,D1,row)                                \
  {                                                      \
    const float* ep_ = et + (size_t)(row) * K_EMB;       \
    D0 = *(const v4f*)(ep_);                             \
    D1 = *(const v4f*)(ep_ + 4);                         \
  }

#define FMA_PHASE(A0_,A1_,B0_,B1_)                                           \
  {                                                                          \
    float as_[8] = {A0_.x,A0_.y,A0_.z,A0_.w, A1_.x,A1_.y,A1_.z,A1_.w};       \
    float bs_[8] = {B0_.x,B0_.y,B0_.z,B0_.w, B1_.x,B1_.y,B1_.z,B1_.w};       \
    _Pragma("unroll")                                                        \
    for (int s_ = 0; s_ < 8; ++s_)                                           \
      _Pragma("unroll")                                                      \
      for (int c_ = 0; c_ < 8; ++c_)                                         \
        acc[s_][c_] = fmaf(as_[s_], bs_[c_], acc[s_][c_]);                   \
  }

__global__ __launch_bounds__(256, 4) void k_amin(const float* __restrict__ xg,
                                                 const float* __restrict__ ws) {
  __shared__ float Xw[4][64][8];           // 8 KB: wave-private [d][s] slabs

  const int t = threadIdx.x;
  const int w = t >> 6;
  const int L = t & 63;
  const int m0 = blockIdx.x * 32 + w * 8;  // this wave's 8 samples

  // wave-local transpose: x[8][64] -> Xw[w][d][s]; same-wave order via lgkmcnt.
  {
    const int s  = L & 7;
    const int dq = (L >> 3) * 8;
    const v4f* xp = (const v4f*)(xg + (size_t)(m0 + s) * D_EMB + dq);
    v4f r0 = xp[0], r1 = xp[1];
    #pragma unroll
    for (int e = 0; e < 4; ++e) {
      Xw[w][dq + 0 + e][s] = r0[e];
      Xw[w][dq + 4 + e][s] = r1[e];
    }
  }

  const float* xrow = &Xw[w][0][0];

  float best[8];
  int   bidx[8];
  #pragma unroll
  for (int s = 0; s < 8; ++s) { best[s] = 3.4e38f; bidx[s] = 0; }

  #pragma unroll 1
  for (int pass = 0; pass < 2; ++pass) {
    const int cb = pass * 512 + L * 8;     // this lane's 8 codes (ascending)
    const float* et = g_Et + cb;

    float acc[8][8];
    #pragma unroll
    for (int s = 0; s < 8; ++s)
      #pragma unroll
      for (int c = 0; c < 8; ++c) acc[s][c] = 0.0f;

    v4f A0, A1, B0, B1;
    v4f NA0, NA1, NB0, NB1;
    LOAD_A(A0, A1, 0)
    LOAD_B(B0, B1, 0)

    #pragma unroll 1
    for (int k2 = 0; k2 < 32; ++k2) {
      const int k = k2 * 2;
      LOAD_A(NA0, NA1, k + 1)
      LOAD_B(NB0, NB1, k + 1)
      FMA_PHASE(A0, A1, B0, B1)
      const int kn = (k2 < 31) ? (k + 2) : 63;  // clamped dummy on last iter
      LOAD_A(A0, A1, kn)
      LOAD_B(B0, B1, kn)
      FMA_PHASE(NA0, NA1, NB0, NB1)
    }

    // fold, code index ascending; score = 0.5||e||^2 - x.e (same argmin)
    const float* hp = ws + 2048 + cb;
    v4f h0 = *(const v4f*)(hp);
    v4f h1 = *(const v4f*)(hp + 4);
    float hs[8] = {h0.x, h0.y, h0.z, h0.w, h1.x, h1.y, h1.z, h1.w};
    #pragma unroll
    for (int c = 0; c < 8; ++c) {
      const int n = cb + c;
      #pragma unroll
      for (int s = 0; s < 8; ++s) {
        float sc = hs[c] - acc[s][c];
        bool lt = sc < best[s];            // strict <: lowest code wins ties
        best[s] = lt ? sc : best[s];
        bidx[s] = lt ? n  : bidx[s];
      }
    }
  }

  // cross-lane argmin butterfly; (score, idx) order = first-min rule
  #pragma unroll
  for (int s = 0; s < 8; ++s) {
    float bs = best[s];
    int   bi = bidx[s];
    #pragma unroll
    for (int i = 0; i < 6; ++i) {
      int off = 32 >> i;
      float ob = __shfl_xor(bs, off, 64);
      int   oi = __shfl_xor(bi, off, 64);
      bool take = (ob < bs) || (ob == bs && oi < bi);
      bs = take ? ob : bs;
      bi = take ? oi : bi;
    }
    bidx[s] = bi;
  }

  #pragma unroll
  for (int s = 0; s < 8; ++s)
    if (L == s) g_ids[m0 + s] = (unsigned int)bidx[s];
}

// ---------------------------------------------------------------------------
// k_store: R8's proven store tail, verbatim geometry (1024 blocks x 128
// samples), ids staged from g_ids. Pure streaming ~640MB -> ~105us.
// ---------------------------------------------------------------------------
__global__ __launch_bounds__(256) void k_store(const float* __restrict__ xg,
                                               const float* __restrict__ emb,
                                               float* __restrict__ out,
                                               float* __restrict__ ws) {
  __shared__ int   ids[128];
  __shared__ float lred[256];

  const int t = threadIdx.x;
  const size_t m0 = (size_t)blockIdx.x * 128;

  if (t < 128) ids[t] = (int)g_ids[m0 + t];
  __syncthreads();

  // quantized + commitment loss (identical to R8's fused store phase)
  float lsum = 0.0f;
  {
    float* qblk = out + QUANT_OFF + m0 * 64;
    const float* xblk = xg + m0 * 64;
    #pragma unroll 1
    for (int it = 0; it < 32; ++it) {
      int f = it * 256 + t;
      int r = f >> 6, d = f & 63;
      float ev = emb[((size_t)ids[r] << 6) + d];
      float xv = xblk[f];
      float dx = ev - xv;
      lsum = fmaf(dx, dx, lsum);
      __builtin_nontemporal_store(xv + dx, qblk + f);   // x + (e-x): ref order
    }
  }
  lred[t] = lsum;
  __syncthreads();
  #pragma unroll
  for (int off = 128; off > 0; off >>= 1) {
    if (t < off) lred[t] += lred[t + off];
    __syncthreads();
  }
  if (t == 0) atomicAdd(ws + 1024, lred[0]);

  // one-hot encodings (128 rows x 1024), R8 verbatim
  v2f* eblk = (v2f*)(out + ENC_OFF) + m0 * 512;
  #pragma unroll 1
  for (int r = 0; r < 128; ++r) {
    int hit = ids[r];                      // broadcast LDS read
    int hc  = hit >> 1;
    v2f one; one.x = (hit & 1) ? 0.0f : 1.0f; one.y = (hit & 1) ? 1.0f : 0.0f;
    v2f zer; zer.x = 0.0f; zer.y = 0.0f;
    v2f* rowp = eblk + (size_t)r * 512;
    __builtin_nontemporal_store((hc == t)       ? one : zer, rowp + t);
    __builtin_nontemporal_store((hc == t + 256) ? one : zer, rowp + t + 256);
  }
}

// ---------------------------------------------------------------------------
// k_count: per-block LDS histogram -> write-only partials (no global atomics).
// Explicit pointer args (hardening: avoid the zero-arg kernel shape).
// ---------------------------------------------------------------------------
__global__ __launch_bounds__(256) void k_count(const unsigned int* __restrict__ ids_g,
                                               unsigned int* __restrict__ pcnt) {
  __shared__ unsigned int hist[K_EMB];
  const int t = threadIdx.x;
  const int b = blockIdx.x;                // 32 blocks x 4096 ids
  #pragma unroll
  for (int j = 0; j < 4; ++j) hist[t + j * 256] = 0u;
  __syncthreads();
  const unsigned int base = b * 4096u;
  #pragma unroll
  for (int i = 0; i < 16; ++i) {
    unsigned int id = ids_g[base + i * 256 + t];
    atomicAdd(&hist[id], 1u);
  }
  __syncthreads();
  #pragma unroll
  for (int j = 0; j < 4; ++j)
    pcnt[b * K_EMB + t + j * 256] = hist[t + j * 256];
}

__global__ __launch_bounds__(256) void k_fin(float* __restrict__ out,
                                             const float* __restrict__ ws,
                                             const unsigned int* __restrict__ pcnt) {
  __shared__ float red[256];
  int t = threadIdx.x;
  float s = 0.0f;
  #pragma unroll
  for (int j = 0; j < 4; ++j) {
    unsigned int cnt = 0u;
    #pragma unroll
    for (int b = 0; b < NCBLK; ++b) cnt += pcnt[b * K_EMB + t + j * 256];
    float p = (float)cnt * (1.0f / (float)N_IN);
    s += p * __logf(p + 1e-10f);
  }
  red[t] = s;
  __syncthreads();
  #pragma unroll
  for (int off = 128; off > 0; off >>= 1) {
    if (t < off) red[t] += red[t + off];
    __syncthreads();
  }
  if (t == 0) {
    out[PERP_OFF] = __expf(-red[0]);
    out[0] = 0.25f * ws[1024] * (1.0f / (float)(N_IN * D_EMB));
  }
}

extern "C" void kernel_launch(void* const* d_in, const int* in_sizes, int n_in,
                              void* d_out, int out_size, void* d_ws, size_t ws_size,
                              hipStream_t stream) {
  (void)in_sizes; (void)n_in; (void)out_size; (void)ws_size;
  const float* x   = (const float*)d_in[0];
  const float* emb = (const float*)d_in[1];
  float* out = (float*)d_out;
  float* ws  = (float*)d_ws;

  unsigned int* idsp;  hipGetSymbolAddress((void**)&idsp,  HIP_SYMBOL(g_ids));
  unsigned int* pcntp; hipGetSymbolAddress((void**)&pcntp, HIP_SYMBOL(g_pcnt));

  hipLaunchKernelGGL(k_prep,  dim3(4),          dim3(256), 0, stream, emb, ws);
  hipLaunchKernelGGL(k_amin,  dim3(N_IN / 32),  dim3(256), 0, stream, x, ws);
  hipLaunchKernelGGL(k_store, dim3(N_IN / 128), dim3(256), 0, stream, x, emb, out, ws);
  hipLaunchKernelGGL(k_count, dim3(NCBLK),      dim3(256), 0, stream, idsp, pcntp);
  hipLaunchKernelGGL(k_fin,   dim3(1),          dim3(256), 0, stream, out, ws, pcntp);
}

// Round 5
// 757.304 us; speedup vs baseline: 1.1653x; 1.1653x over previous
//
#include <hip/hip_runtime.h>

typedef float v2f __attribute__((ext_vector_type(2)));
typedef float v4f __attribute__((ext_vector_type(4)));

#define N_IN   131072
#define K_EMB  1024
#define D_EMB  64
#define QUANT_OFF 1
#define PERP_OFF  (1 + N_IN * D_EMB)      /* 8388609 */
#define ENC_OFF   (PERP_OFF + 1)          /* 8388610: %16==8 -> float2 stores only */

// R13: fused wave-autonomous kernel, 16 samples/wave x 4 codes/lane.
// R12 post-mortem: amin WITHOUT stores still ~390us -> store-thrash theory
// refuted. Real wall: per-CU VMEM return path. S=8 reads 2KB B per k-step
// per wave (4GB total) = 64 B/cy/CU at the VALU floor = the L1 port limit.
// S=16 halves that to 1KB/k (2GB, 32 B/cy/CU) while keeping acc at 64 VGPRs
// via 4 codes/lane x 4 code-passes. Stores re-fused (R8 proved fusion
// overlaps the write stream; it costs ~5 B/cy/CU of the reclaimed headroom).
__device__ float g_Et[D_EMB * K_EMB];     // Et[d][c] transposed codebook

// ws layout (4-byte units): [0..1023] counts (u32), [1024] loss (f32),
// [2048..3071] half squared norms (f32).

__global__ __launch_bounds__(256) void k_prep(const float* __restrict__ emb,
                                              float* __restrict__ ws) {
  int k = blockIdx.x * 256 + threadIdx.x;  // grid=4 -> k in [0,1024)
  ((unsigned int*)ws)[k] = 0u;             // zero counts (re-poison safe)
  if (k == 0) ws[1024] = 0.0f;
  const float* e = emb + (size_t)k * D_EMB;
  double s = 0.0;
  #pragma unroll
  for (int d = 0; d < D_EMB; ++d) {
    float v = e[d];
    s += (double)v * (double)v;
    g_Et[d * K_EMB + k] = v;               // coalesced per d
  }
  ws[2048 + k] = (float)(0.5 * s);
}

#define LOAD_A(D0,D1,D2,D3,row)                          \
  {                                                      \
    const float* xr_ = xrow + (row) * 16;                \
    D0 = *(const v4f*)(xr_ + 0);                         \
    D1 = *(const v4f*)(xr_ + 4);                         \
    D2 = *(const v4f*)(xr_ + 8);                         \
    D3 = *(const v4f*)(xr_ + 12);                        \
  }

#define LOAD_B(D0,row)                                   \
  { D0 = *(const v4f*)(et + (size_t)(row) * K_EMB); }

#define FMA_PHASE(A0_,A1_,A2_,A3_,B0_)                                       \
  {                                                                          \
    float as_[16] = {A0_.x,A0_.y,A0_.z,A0_.w, A1_.x,A1_.y,A1_.z,A1_.w,       \
                     A2_.x,A2_.y,A2_.z,A2_.w, A3_.x,A3_.y,A3_.z,A3_.w};      \
    float bs_[4]  = {B0_.x,B0_.y,B0_.z,B0_.w};                               \
    _Pragma("unroll")                                                        \
    for (int s_ = 0; s_ < 16; ++s_)                                          \
      _Pragma("unroll")                                                      \
      for (int c_ = 0; c_ < 4; ++c_)                                         \
        acc[s_][c_] = fmaf(as_[s_], bs_[c_], acc[s_][c_]);                   \
  }

__global__ __launch_bounds__(256, 3) void k_main(const float* __restrict__ xg,
                                                 const float* __restrict__ emb,
                                                 float* __restrict__ out,
                                                 float* __restrict__ ws) {
  __shared__ float Xw[4][64][16];          // 16 KB: wave-private [d][s] slabs

  const int t = threadIdx.x;
  const int w = t >> 6;                    // wave in block
  const int L = t & 63;                    // lane
  const int m0 = blockIdx.x * 64 + w * 16; // this wave's 16 samples

  // wave-local transpose: x[16][64] -> Xw[w][d][s]; same-wave order via
  // lgkmcnt, no barrier (only this wave touches Xw[w]).
  {
    const int s  = L & 15;
    const int dq = (L >> 4) * 16;          // 4 lane-groups x 16 dims
    const v4f* xp = (const v4f*)(xg + (size_t)(m0 + s) * D_EMB + dq);
    v4f r0 = xp[0], r1 = xp[1], r2 = xp[2], r3 = xp[3];
    #pragma unroll
    for (int e = 0; e < 4; ++e) {
      Xw[w][dq + 0  + e][s] = r0[e];
      Xw[w][dq + 4  + e][s] = r1[e];
      Xw[w][dq + 8  + e][s] = r2[e];
      Xw[w][dq + 12 + e][s] = r3[e];
    }
  }

  const float* xrow = &Xw[w][0][0];

  float best[16];
  int   bidx[16];
  #pragma unroll
  for (int s = 0; s < 16; ++s) { best[s] = 3.4e38f; bidx[s] = 0; }

  #pragma unroll 1
  for (int pass = 0; pass < 4; ++pass) {
    const int cb = pass * 256 + L * 4;     // this lane's 4 codes (ascending)
    const float* et = g_Et + cb;

    float acc[16][4];
    #pragma unroll
    for (int s = 0; s < 16; ++s)
      #pragma unroll
      for (int c = 0; c < 4; ++c) acc[s][c] = 0.0f;

    v4f A0, A1, A2, A3, B0;                // current k
    v4f NA0, NA1, NA2, NA3, NB0;           // next k (prefetch)
    LOAD_A(A0, A1, A2, A3, 0)
    LOAD_B(B0, 0)

    #pragma unroll 1
    for (int k2 = 0; k2 < 32; ++k2) {
      const int k = k2 * 2;
      LOAD_A(NA0, NA1, NA2, NA3, k + 1)    // prefetch k+1 under compute of k
      LOAD_B(NB0, k + 1)
      FMA_PHASE(A0, A1, A2, A3, B0)
      const int kn = (k2 < 31) ? (k + 2) : 63;  // clamped dummy on last iter
      LOAD_A(A0, A1, A2, A3, kn)
      LOAD_B(B0, kn)
      FMA_PHASE(NA0, NA1, NA2, NA3, NB0)
    }

    // fold, code index ascending; score = 0.5||e||^2 - x.e (same argmin).
    v4f h0 = *(const v4f*)(ws + 2048 + cb);
    float hs[4] = {h0.x, h0.y, h0.z, h0.w};
    #pragma unroll
    for (int c = 0; c < 4; ++c) {
      const int n = cb + c;
      #pragma unroll
      for (int s = 0; s < 16; ++s) {
        float sc = hs[c] - acc[s][c];
        bool lt = sc < best[s];            // strict <: lowest code wins ties
        best[s] = lt ? sc : best[s];
        bidx[s] = lt ? n  : bidx[s];
      }
    }
  }

  // cross-lane argmin butterfly; (score, idx) order = first-min rule.
  // Result lands in ALL lanes.
  #pragma unroll
  for (int s = 0; s < 16; ++s) {
    float bs = best[s];
    int   bi = bidx[s];
    #pragma unroll
    for (int i = 0; i < 6; ++i) {
      int off = 32 >> i;
      float ob = __shfl_xor(bs, off, 64);
      int   oi = __shfl_xor(bi, off, 64);
      bool take = (ob < bs) || (ob == bs && oi < bi);
      bs = take ? ob : bs;
      bi = take ? oi : bi;
    }
    bidx[s] = bi;
  }

  // counts: one atomic per sample (lane s handles sample s)
  #pragma unroll
  for (int s = 0; s < 16; ++s)
    if (L == s) atomicAdd((unsigned int*)ws + bidx[s], 1u);

  // quantized + commitment loss (q = x + (e - x): ref order)
  float lsum = 0.0f;
  #pragma unroll
  for (int s = 0; s < 16; ++s) {
    float xv = xg[(size_t)(m0 + s) * D_EMB + L];
    float ev = emb[(size_t)bidx[s] * D_EMB + L];   // wave-uniform row
    float dx = ev - xv;
    lsum = fmaf(dx, dx, lsum);
    __builtin_nontemporal_store(xv + dx,
        out + QUANT_OFF + (size_t)(m0 + s) * D_EMB + L);
  }
  #pragma unroll
  for (int i = 0; i < 6; ++i) lsum += __shfl_xor(lsum, 32 >> i, 64);
  if (L == 0) atomicAdd(ws + 1024, lsum);

  // one-hot encodings: 16 rows x 1024; lane L covers v2f slots L+64q
  v2f* eb = (v2f*)(out + ENC_OFF);
  #pragma unroll
  for (int s = 0; s < 16; ++s) {
    int hit = bidx[s];
    int hc  = hit >> 1;
    v2f one; one.x = (hit & 1) ? 0.0f : 1.0f; one.y = (hit & 1) ? 1.0f : 0.0f;
    v2f zer; zer.x = 0.0f; zer.y = 0.0f;
    v2f* rowp = eb + (size_t)(m0 + s) * 512;
    #pragma unroll
    for (int q = 0; q < 8; ++q)
      __builtin_nontemporal_store((hc == L + 64 * q) ? one : zer,
                                  rowp + L + 64 * q);
  }
}

__global__ __launch_bounds__(256) void k_fin(float* __restrict__ out,
                                             const float* __restrict__ ws) {
  __shared__ float red[256];
  const unsigned int* counts = (const unsigned int*)ws;
  int t = threadIdx.x;
  float s = 0.0f;
  #pragma unroll
  for (int i = 0; i < 4; ++i) {
    float p = (float)counts[t + i * 256] * (1.0f / (float)N_IN);
    s += p * __logf(p + 1e-10f);
  }
  red[t] = s;
  __syncthreads();
  #pragma unroll
  for (int off = 128; off > 0; off >>= 1) {
    if (t < off) red[t] += red[t + off];
    __syncthreads();
  }
  if (t == 0) {
    out[PERP_OFF] = __expf(-red[0]);
    out[0] = 0.25f * ws[1024] * (1.0f / (float)(N_IN * D_EMB));
  }
}

extern "C" void kernel_launch(void* const* d_in, const int* in_sizes, int n_in,
                              void* d_out, int out_size, void* d_ws, size_t ws_size,
                              hipStream_t stream) {
  (void)in_sizes; (void)n_in; (void)out_size; (void)ws_size;
  const float* x   = (const float*)d_in[0];
  const float* emb = (const float*)d_in[1];
  float* out = (float*)d_out;
  float* ws  = (float*)d_ws;

  hipLaunchKernelGGL(k_prep, dim3(4),         dim3(256), 0, stream, emb, ws);
  hipLaunchKernelGGL(k_main, dim3(N_IN / 64), dim3(256), 0, stream, x, emb, out, ws);
  hipLaunchKernelGGL(k_fin,  dim3(1),         dim3(256), 0, stream, out, ws);
}